// Round 19
// baseline (312.849 us; speedup 1.0000x reference)
//
#include <hip/hip_runtime.h>
#include <stdint.h>

#define B_ 32
#define H_ 56
#define W_ 56
#define N_ 3136
#define C_ 256
#define NH_ 8
#define HD_ 32
#define A_ 49
#define NCH_ 7
#define CHK_ 448
#define SCALE_ 0.17677669529663687f

typedef _Float16 h16;
typedef __attribute__((ext_vector_type(4))) _Float16 h16x4;
typedef __attribute__((ext_vector_type(8))) _Float16 h16x8;
typedef __attribute__((ext_vector_type(4))) float f32x4;

// global -> LDS direct DMA, 16B per lane
__device__ __forceinline__ void gload16(const void* g, void* l) {
  __builtin_amdgcn_global_load_lds(
      (const __attribute__((address_space(1))) unsigned int*)(uintptr_t)g,
      (__attribute__((address_space(3))) unsigned int*)(unsigned int)(uintptr_t)l,
      16, 0, 0);
}

// ---------------------------------------------------------------------------
// Bias precompute: position_bias [NH][A][N] f16, agent_bias^T [NH][A][N] f16
// ---------------------------------------------------------------------------
__global__ __launch_bounds__(256)
void bias_kernel(const float* __restrict__ an, const float* __restrict__ na,
                 const float* __restrict__ ah, const float* __restrict__ aw,
                 const float* __restrict__ ha, const float* __restrict__ wa,
                 h16* __restrict__ posb, h16* __restrict__ agbt)
{
  const int hh = blockIdx.x / A_;
  const int ag = blockIdx.x % A_;
  __shared__ float an7[A_], na7[A_], ahv[H_], awv[W_], hav[H_], wav[W_];
  const int tid = threadIdx.x;
  if (tid < A_) {
    an7[tid] = an[(hh*A_ + ag)*A_ + tid];
    na7[tid] = na[(hh*A_ + ag)*A_ + tid];
  }
  if (tid < H_) {
    ahv[tid] = ah[(hh*A_ + ag)*H_ + tid];
    awv[tid] = aw[(hh*A_ + ag)*W_ + tid];
    hav[tid] = ha[(hh*H_ + tid)*A_ + ag];
    wav[tid] = wa[(hh*W_ + tid)*A_ + ag];
  }
  __syncthreads();
  for (int t = tid; t < N_; t += 256) {
    const int ty = t / W_, tx = t % W_;
    const float py = (ty + 0.5f)*0.125f - 0.5f;
    const float px = (tx + 0.5f)*0.125f - 0.5f;
    const int iy = (int)floorf(py), ix = (int)floorf(px);
    const float fy = py - (float)iy, fx = px - (float)ix;
    const int iy0 = min(max(iy, 0), 6), iy1 = min(iy + 1, 6);
    const int ix0 = min(max(ix, 0), 6), ix1 = min(ix + 1, 6);
    const float w00 = (1.f-fy)*(1.f-fx), w01 = (1.f-fy)*fx;
    const float w10 = fy*(1.f-fx),       w11 = fy*fx;
    const float ban = w00*an7[iy0*7+ix0] + w01*an7[iy0*7+ix1]
                    + w10*an7[iy1*7+ix0] + w11*an7[iy1*7+ix1];
    const float bna = w00*na7[iy0*7+ix0] + w01*na7[iy0*7+ix1]
                    + w10*na7[iy1*7+ix0] + w11*na7[iy1*7+ix1];
    posb[((size_t)(hh*A_ + ag))*N_ + t] = (h16)(ban + ahv[ty] + awv[tx]);
    agbt[((size_t)(hh*A_ + ag))*N_ + t] = (h16)(bna + hav[ty] + wav[tx]);
  }
}

// ---------------------------------------------------------------------------
// f32 -> f16 conversion of x
// ---------------------------------------------------------------------------
__global__ __launch_bounds__(256)
void convx_kernel(const float* __restrict__ x, h16* __restrict__ xh)
{
  const size_t nchunk = (size_t)B_*N_*C_/8;
  const size_t stride = (size_t)gridDim.x * 256;
  for (size_t i = blockIdx.x*256 + threadIdx.x; i < nchunk; i += stride) {
    const float4 u = ((const float4*)x)[i*2];
    const float4 v = ((const float4*)x)[i*2+1];
    h16x8 o;
    o[0]=(h16)u.x; o[1]=(h16)u.y; o[2]=(h16)u.z; o[3]=(h16)u.w;
    o[4]=(h16)v.x; o[5]=(h16)v.y; o[6]=(h16)v.z; o[7]=(h16)v.w;
    ((h16x8*)xh)[i] = o;
  }
}

// transpose+convert weights: wtq[768][256], wtp[256][256] f16,
// plus dwc weight table w9t[10][256] f16 (rows 0..8 = taps, row 9 = bias)
__global__ __launch_bounds__(256)
void convw_kernel(const float* __restrict__ qkvw, const float* __restrict__ projw,
                  const float* __restrict__ dwcw, const float* __restrict__ dwcb,
                  h16* __restrict__ wtq, h16* __restrict__ wtp, h16* __restrict__ w9t)
{
  const int bid = blockIdx.x, k = threadIdx.x;
  if (bid < 768) {
    wtq[bid*256 + k] = (h16)qkvw[(size_t)k*768 + bid];
  } else if (bid < 1024) {
    const int n = bid - 768;
    wtp[n*256 + k] = (h16)projw[(size_t)k*256 + n];
  } else {
    const int row = bid - 1024;            // 0..9
    w9t[row*256 + k] = (h16)(row < 9 ? dwcw[k*9 + row] : dwcb[k]);
  }
}

// ---------------------------------------------------------------------------
// f16 MFMA GEMM core: 128x128 tile, BK=32, 4 waves, double-buffered with
// COUNTED vmcnt (T4): stage(next) -> vmcnt(4) -> barrier -> MFMA -> barrier.
// ---------------------------------------------------------------------------
__device__ __forceinline__ void gemm_tile_128(
    const h16* __restrict__ Ag, const h16* __restrict__ Bg,
    int m0, int n0, char* lds, f32x4 acc[4][4], int lane, int wr, int wc, int tid)
{
  int aoff[4], boff[4];
  #pragma unroll
  for (int r = 0; r < 4; ++r) {
    const int row = wr*64 + r*16 + (lane & 15);
    const int ps  = (lane >> 4) ^ ((row >> 1) & 3);
    aoff[r] = row*64 + ps*16;
  }
  #pragma unroll
  for (int c = 0; c < 4; ++c) {
    const int nrow = wc*64 + c*16 + (lane & 15);
    const int ps   = (lane >> 4) ^ ((nrow >> 1) & 3);
    boff[c] = 8192 + nrow*64 + ps*16;
  }
  const int i0 = tid, i1 = tid + 256;
  const int r0 = i0 >> 2, s0 = (i0 & 3) ^ ((r0 >> 1) & 3);
  const int r1 = i1 >> 2, s1 = (i1 & 3) ^ ((r1 >> 1) & 3);

  auto stage = [&](int buf, int k0) {
    char* l = lds + buf*16384;
    gload16(Ag + (size_t)(m0 + r0)*256 + k0 + s0*8, l + i0*16);
    gload16(Ag + (size_t)(m0 + r1)*256 + k0 + s1*8, l + i1*16);
    gload16(Bg + (size_t)(n0 + r0)*256 + k0 + s0*8, l + 8192 + i0*16);
    gload16(Bg + (size_t)(n0 + r1)*256 + k0 + s1*8, l + 8192 + i1*16);
  };

  stage(0, 0);                     // 4 DMAs in flight
  int cur = 0;
  #pragma unroll
  for (int k0 = 0; k0 < 256; k0 += 32) {
    if (k0 + 32 < 256) {
      stage(cur ^ 1, k0 + 32);     // +4 DMAs (next tile)
      asm volatile("s_waitcnt vmcnt(4)" ::: "memory");   // own cur-tile DMAs done
    } else {
      asm volatile("s_waitcnt vmcnt(0)" ::: "memory");
    }
    __builtin_amdgcn_s_barrier();            // all waves' cur-tile writes done
    __builtin_amdgcn_sched_barrier(0);       // fence: no ds_read hoisting
    char* l = lds + cur*16384;
    h16x8 af[4], bf[4];
    #pragma unroll
    for (int r = 0; r < 4; ++r) af[r] = *(const h16x8*)(l + aoff[r]);
    #pragma unroll
    for (int c = 0; c < 4; ++c) bf[c] = *(const h16x8*)(l + boff[c]);
    #pragma unroll
    for (int r = 0; r < 4; ++r)
      #pragma unroll
      for (int c = 0; c < 4; ++c)
        acc[r][c] = __builtin_amdgcn_mfma_f32_16x16x32_f16(af[r], bf[c], acc[r][c], 0, 0, 0);
    __builtin_amdgcn_s_barrier();            // read-release: cur may be overwritten
    cur ^= 1;
  }
}

// QKV: grid 4704 = 784 m-tiles x 6 n-tiles; XCD-bijective swizzle (scalar epilogue)
__global__ __launch_bounds__(256)
void gemm_qkv_mfma(const h16* __restrict__ xh, const h16* __restrict__ wtq,
                   const float* __restrict__ qkvb,
                   h16* __restrict__ q, h16* __restrict__ k, h16* __restrict__ v)
{
  __shared__ __align__(16) char lds[32768];
  const int tid = threadIdx.x, lane = tid & 63, wid = tid >> 6;
  const int wr = wid & 1, wc = wid >> 1;
  const int bid = blockIdx.x;
  const int xcd = bid & 7, j = bid >> 3;           // j in [0,588)
  const int mt = xcd + 8*(j/6), nt = j - 6*(j/6);  // 784 = 98*8 exact
  const int m0 = mt*128, n0 = nt*128;
  f32x4 acc[4][4] = {};
  gemm_tile_128(xh, wtq, m0, n0, lds, acc, lane, wr, wc, tid);
  #pragma unroll
  for (int r = 0; r < 4; ++r) {
    #pragma unroll
    for (int reg = 0; reg < 4; ++reg) {
      const int m = m0 + wr*64 + r*16 + (lane >> 4)*4 + reg;
      const int bb = m / N_, t = m % N_;
      #pragma unroll
      for (int c = 0; c < 4; ++c) {
        const int n = n0 + wc*64 + c*16 + (lane & 15);
        const float val = acc[r][c][reg] + qkvb[n];
        const int part = n >> 8, cc = n & 255, hh = cc >> 5, d = cc & 31;
        h16* dst = (part == 0) ? q : ((part == 1) ? k : v);
        dst[(((size_t)(bb*NH_ + hh))*N_ + t)*HD_ + d] = (h16)val;
      }
    }
  }
}

// Proj: grid 1568 = 784 m-tiles x 2 n-tiles, same swizzle idea
__global__ __launch_bounds__(256)
void gemm_proj_mfma(const h16* __restrict__ preh, const h16* __restrict__ wtp,
                    const float* __restrict__ projb, float* __restrict__ out)
{
  __shared__ __align__(16) char lds[32768];
  const int tid = threadIdx.x, lane = tid & 63, wid = tid >> 6;
  const int wr = wid & 1, wc = wid >> 1;
  const int bid = blockIdx.x;
  const int xcd = bid & 7, j = bid >> 3;           // j in [0,196)
  const int mt = xcd + 8*(j >> 1), nt = j & 1;     // 784 = 98*8 exact
  const int m0 = mt*128, n0 = nt*128;
  f32x4 acc[4][4] = {};
  gemm_tile_128(preh, wtp, m0, n0, lds, acc, lane, wr, wc, tid);
  #pragma unroll
  for (int r = 0; r < 4; ++r) {
    #pragma unroll
    for (int reg = 0; reg < 4; ++reg) {
      const int m = m0 + wr*64 + r*16 + (lane >> 4)*4 + reg;
      #pragma unroll
      for (int c = 0; c < 4; ++c) {
        const int n = n0 + wc*64 + c*16 + (lane & 15);
        out[(size_t)m*256 + n] = acc[r][c][reg] + projb[n];
      }
    }
  }
}

// ---------------------------------------------------------------------------
// Agent pooling: 8x8 mean of q image -> agent [b][nh][49][32] (f32)
// ---------------------------------------------------------------------------
__global__ __launch_bounds__(64)
void pool_kernel(const h16* __restrict__ q, float* __restrict__ agent)
{
  const int blk = blockIdx.x;
  const int ag = blk % A_;
  const int rem = blk / A_;
  const int tid = threadIdx.x;
  const int d = tid & 31, half = tid >> 5;
  const int ay = ag / 7, ax = ag % 7;
  const size_t base = (size_t)rem * N_ * HD_;
  float s = 0.f;
  #pragma unroll
  for (int it = 0; it < 32; ++it) {
    const int yy = half*4 + (it >> 3), xx = it & 7;
    const int t = (ay*8 + yy)*W_ + ax*8 + xx;
    s += (float)q[base + (size_t)t*HD_ + d];
  }
  s += __shfl_down(s, 32, 64);
  if (tid < 32) agent[(size_t)rem*A_*HD_ + ag*HD_ + d] = s * (1.f/64.f);
}

// ---------------------------------------------------------------------------
// Stage 1a (MFMA): flash over 7 key-tiles of 64; M=64 (49 agents + pad)
// ---------------------------------------------------------------------------
__global__ __launch_bounds__(256)
void stage1a_mfma(const h16* __restrict__ kmat, const h16* __restrict__ vmat,
                  const float* __restrict__ agent, const h16* __restrict__ posb,
                  float* __restrict__ pm, float* __restrict__ pl, float* __restrict__ pacc)
{
  __shared__ __align__(16) h16 Kl[64*32];
  __shared__ __align__(16) h16 Vt[32*72];
  __shared__ __align__(16) h16 Sl[64*72];
  const int tid = threadIdx.x, lane = tid & 63, wid = tid >> 6;
  const int bx = blockIdx.x;
  const int ch = bx % NCH_;
  const int rem = bx / NCH_;
  const int hh = rem & 7;
  const size_t kvbase = (size_t)rem * N_ * HD_;
  const size_t agbase = (size_t)rem * A_ * HD_;
  const h16* pb = posb + (size_t)hh*A_*N_;

  const int arow = wid*16 + (lane & 15);
  const int kc = (lane >> 4) * 8;
  h16x8 a_ag = {};
  if (arow < A_) {
    #pragma unroll
    for (int j = 0; j < 8; ++j)
      a_ag[j] = (h16)(agent[agbase + (size_t)arow*HD_ + kc + j] * SCALE_);
  }

  const int r_k = tid >> 2;
  const int s_k = (tid & 3) ^ ((r_k >> 1) & 3);
  const int rowm = (lane >> 4) * 4;
  const int agrow0 = wid*16 + rowm;

  float m_r[4], l_r[4];
  #pragma unroll
  for (int r = 0; r < 4; ++r) { m_r[r] = -1e30f; l_r[r] = 0.f; }
  f32x4 accv[2] = {};

  for (int it = 0; it < 7; ++it) {
    const int t0 = ch*CHK_ + it*64;
    __syncthreads();
    gload16(kmat + kvbase + (size_t)(t0 + r_k)*HD_ + s_k*8, ((char*)Kl) + tid*16);
    const h16x8 vv = *(const h16x8*)&vmat[kvbase + (size_t)(t0 + lane)*HD_ + wid*8];
    #pragma unroll
    for (int j = 0; j < 8; ++j) Vt[(wid*8 + j)*72 + lane] = vv[j];
    __syncthreads();

    float sv[4][4];
    #pragma unroll
    for (int c = 0; c < 4; ++c) {
      const int kr = c*16 + (lane & 15);
      const int ph = (lane >> 4) ^ ((kr >> 1) & 3);
      const h16x8 bf = *(const h16x8*)&Kl[kr*32 + ph*8];
      const f32x4 sc = __builtin_amdgcn_mfma_f32_16x16x32_f16(a_ag, bf, (f32x4){0.f,0.f,0.f,0.f}, 0, 0, 0);
      #pragma unroll
      for (int reg = 0; reg < 4; ++reg) sv[reg][c] = sc[reg];
    }
    #pragma unroll
    for (int reg = 0; reg < 4; ++reg) {
      const int ag = agrow0 + reg;
      if (ag < A_) {
        #pragma unroll
        for (int c = 0; c < 4; ++c)
          sv[reg][c] += (float)pb[(size_t)ag*N_ + t0 + c*16 + (lane & 15)];
      } else {
        #pragma unroll
        for (int c = 0; c < 4; ++c) sv[reg][c] = -1e30f;
      }
      float rm = fmaxf(fmaxf(sv[reg][0], sv[reg][1]), fmaxf(sv[reg][2], sv[reg][3]));
      rm = fmaxf(rm, __shfl_xor(rm, 1));
      rm = fmaxf(rm, __shfl_xor(rm, 2));
      rm = fmaxf(rm, __shfl_xor(rm, 4));
      rm = fmaxf(rm, __shfl_xor(rm, 8));
      const float mn = fmaxf(m_r[reg], rm);
      const float f = __expf(m_r[reg] - mn);
      m_r[reg] = mn;
      float rs = 0.f;
      #pragma unroll
      for (int c = 0; c < 4; ++c) {
        const float p = __expf(sv[reg][c] - mn);
        sv[reg][c] = p;
        rs += p;
      }
      rs += __shfl_xor(rs, 1); rs += __shfl_xor(rs, 2);
      rs += __shfl_xor(rs, 4); rs += __shfl_xor(rs, 8);
      l_r[reg] = l_r[reg]*f + rs;
      accv[0][reg] *= f;
      accv[1][reg] *= f;
      const int row = agrow0 + reg;
      #pragma unroll
      for (int c = 0; c < 4; ++c)
        Sl[row*72 + c*16 + (lane & 15)] = (h16)sv[reg][c];
    }
    __syncthreads();
    const int srow = wid*16 + (lane & 15);
    #pragma unroll
    for (int ks = 0; ks < 2; ++ks) {
      const h16x8 pf = *(const h16x8*)&Sl[srow*72 + ks*32 + (lane >> 4)*8];
      #pragma unroll
      for (int c2 = 0; c2 < 2; ++c2) {
        const int d = c2*16 + (lane & 15);
        const h16x8 vf = *(const h16x8*)&Vt[d*72 + ks*32 + (lane >> 4)*8];
        accv[c2] = __builtin_amdgcn_mfma_f32_16x16x32_f16(pf, vf, accv[c2], 0, 0, 0);
      }
    }
  }

  #pragma unroll
  for (int reg = 0; reg < 4; ++reg) {
    const int ag = agrow0 + reg;
    if (ag < A_) {
      if ((lane & 15) == 0) {
        pm[bx*A_ + ag] = m_r[reg];
        pl[bx*A_ + ag] = l_r[reg];
      }
      #pragma unroll
      for (int c2 = 0; c2 < 2; ++c2)
        pacc[(size_t)bx*(A_*HD_) + (size_t)ag*HD_ + c2*16 + (lane & 15)] = accv[c2][reg];
    }
  }
}

// Stage 1b: combine 7 chunk-partials -> agent_v
__global__ __launch_bounds__(256)
void stage1b_kernel(const float* __restrict__ pm, const float* __restrict__ pl,
                    const float* __restrict__ pacc, float* __restrict__ agv)
{
  const int rem = blockIdx.x;
  __shared__ float fs[NCH_*A_];
  const int tid = threadIdx.x;
  if (tid < A_) {
    float m = -1e30f;
    #pragma unroll
    for (int ch = 0; ch < NCH_; ++ch) m = fmaxf(m, pm[(rem*NCH_+ch)*A_ + tid]);
    float e[NCH_], l = 0.f;
    #pragma unroll
    for (int ch = 0; ch < NCH_; ++ch) {
      e[ch] = __expf(pm[(rem*NCH_+ch)*A_ + tid] - m);
      l += e[ch] * pl[(rem*NCH_+ch)*A_ + tid];
    }
    const float inv = 1.f / l;
    #pragma unroll
    for (int ch = 0; ch < NCH_; ++ch) fs[ch*A_ + tid] = e[ch] * inv;
  }
  __syncthreads();
  for (int idx = tid; idx < A_*HD_; idx += 256) {
    const int ag = idx >> 5;
    float s = 0.f;
    #pragma unroll
    for (int ch = 0; ch < NCH_; ++ch)
      s += fs[ch*A_ + ag] * pacc[((size_t)(rem*NCH_+ch))*(A_*HD_) + idx];
    agv[(size_t)rem*(A_*HD_) + idx] = s;
  }
}

// ---------------------------------------------------------------------------
// Stage 2 (MFMA) + FUSED depthwise conv.
// LDS = 40,960 B exactly (4 blocks/CU): Asw 4KB + AVt 4KB (slot-XOR swizzled
// [32][8x16B]) + 4 x per-wave P-tile 8KB (slot-XOR swizzled [64][8x16B]).
// Av transpose buffer keeps the proven stride-40 layout inside the P region.
// ---------------------------------------------------------------------------
__global__ __launch_bounds__(256)
void stage2_mfma(const h16* __restrict__ qmat, const float* __restrict__ agent,
                 const float* __restrict__ agv, const h16* __restrict__ agbt,
                 const h16* __restrict__ vmat, const h16* __restrict__ w9t,
                 h16* __restrict__ preh)
{
  __shared__ __align__(16) char lds2[40960];
  h16*  Asw  = (h16*)lds2;                     // [64][32] agent, swizzled (as before)
  char* AVtB = lds2 + 4096;                    // [32 d][8 slots x16B], slot ^= d&7
  const int tid = threadIdx.x, lane = tid & 63, wid = tid >> 6;
  const int b = blockIdx.y >> 3, hh = blockIdx.y & 7;
  const size_t agbase = (size_t)(b*NH_ + hh)*A_*HD_;

  for (int i = tid; i < 64*32; i += 256) Asw[i] = (h16)0.f;
  ((f32x4*)AVtB)[tid] = (f32x4){0.f, 0.f, 0.f, 0.f};   // 256*16B = 4096B zeroed
  __syncthreads();
  for (int i = tid; i < A_*HD_; i += 256) {
    const int a = i >> 5, d = i & 31;
    Asw[a*32 + (((d >> 3) ^ ((a >> 1) & 3)))*8 + (d & 7)] = (h16)(agent[agbase + i] * SCALE_);
    *(h16*)(AVtB + d*128 + (((a >> 3) ^ (d & 7))*16) + (a & 7)*2) = (h16)agv[agbase + i];
  }
  __syncthreads();

  const int t0 = blockIdx.x*256 + wid*64;
  if (t0 >= N_) return;

  char* PlB = lds2 + 8192 + wid*8192;          // per-wave [64 rows][8 slots x16B]
  const h16* qbase = qmat + (size_t)(b*NH_ + hh)*N_*HD_;
  const h16* agbt_h = agbt + (size_t)hh*A_*N_;
  const int l15 = lane & 15, g = lane >> 4;

  h16x8 bq[4];
  #pragma unroll
  for (int c = 0; c < 4; ++c) {
    const int a = c*16 + l15;
    const int ph = g ^ ((a >> 1) & 3);
    bq[c] = *(const h16x8*)&Asw[a*32 + ph*8];
  }
  h16x8 aq[4];
  #pragma unroll
  for (int rt = 0; rt < 4; ++rt)
    aq[rt] = *(const h16x8*)&qbase[(size_t)(t0 + rt*16 + l15)*HD_ + g*8];

  f32x4 sc[4][4];
  #pragma unroll
  for (int rt = 0; rt < 4; ++rt)
    #pragma unroll
    for (int c = 0; c < 4; ++c)
      sc[rt][c] = __builtin_amdgcn_mfma_f32_16x16x32_f16(aq[rt], bq[c], (f32x4){0.f,0.f,0.f,0.f}, 0, 0, 0);

  #pragma unroll
  for (int rt = 0; rt < 4; ++rt) {
    float sv[4][4];
    #pragma unroll
    for (int c = 0; c < 4; ++c) {
      const int a = c*16 + l15;
      if (a < A_) {
        const h16x4 bias = *(const h16x4*)&agbt_h[(size_t)a*N_ + t0 + rt*16 + g*4];
        sv[0][c] = sc[rt][c][0] + (float)bias[0];
        sv[1][c] = sc[rt][c][1] + (float)bias[1];
        sv[2][c] = sc[rt][c][2] + (float)bias[2];
        sv[3][c] = sc[rt][c][3] + (float)bias[3];
      } else {
        sv[0][c] = sv[1][c] = sv[2][c] = sv[3][c] = -1e30f;
      }
    }
    #pragma unroll
    for (int reg = 0; reg < 4; ++reg) {
      float rm = fmaxf(fmaxf(sv[reg][0], sv[reg][1]), fmaxf(sv[reg][2], sv[reg][3]));
      rm = fmaxf(rm, __shfl_xor(rm, 1));
      rm = fmaxf(rm, __shfl_xor(rm, 2));
      rm = fmaxf(rm, __shfl_xor(rm, 4));
      rm = fmaxf(rm, __shfl_xor(rm, 8));
      float rs = 0.f;
      #pragma unroll
      for (int c = 0; c < 4; ++c) {
        const float p = __expf(sv[reg][c] - rm);
        sv[reg][c] = p;
        rs += p;
      }
      rs += __shfl_xor(rs, 1); rs += __shfl_xor(rs, 2);
      rs += __shfl_xor(rs, 4); rs += __shfl_xor(rs, 8);
      const float inv = 1.f / rs;
      const int row = rt*16 + g*4 + reg;
      #pragma unroll
      for (int c = 0; c < 4; ++c)
        *(h16*)(PlB + row*128 + (((c*2 + (l15 >> 3)) ^ (row & 7))*16) + (l15 & 7)*2)
            = (h16)(sv[reg][c] * inv);
    }
  }

  h16x8 vf[2][2];
  #pragma unroll
  for (int ks = 0; ks < 2; ++ks)
    #pragma unroll
    for (int c2 = 0; c2 < 2; ++c2)
      vf[ks][c2] = *(const h16x8*)(AVtB + (c2*16 + l15)*128 + (((ks*4 + g) ^ (l15 & 7))*16));

  f32x4 av[4][2] = {};
  #pragma unroll
  for (int rt = 0; rt < 4; ++rt) {
    const int prow = rt*16 + l15;
    #pragma unroll
    for (int ks = 0; ks < 2; ++ks) {
      const h16x8 pf = *(const h16x8*)(PlB + prow*128 + (((ks*4 + g) ^ (l15 & 7))*16));
      #pragma unroll
      for (int c2 = 0; c2 < 2; ++c2)
        av[rt][c2] = __builtin_amdgcn_mfma_f32_16x16x32_f16(pf, vf[ks][c2], av[rt][c2], 0, 0, 0);
    }
  }

  // --- transpose av through per-wave LDS (stride 40 = 80B rows, 16B-aligned) ---
  h16* Av = (h16*)PlB;                         // [64 tokens][40 h16]
  #pragma unroll
  for (int rt = 0; rt < 4; ++rt)
    #pragma unroll
    for (int c2 = 0; c2 < 2; ++c2)
      #pragma unroll
      for (int reg = 0; reg < 4; ++reg)
        Av[(rt*16 + g*4 + reg)*40 + c2*16 + l15] = (h16)av[rt][c2][reg];

  // --- fused depthwise 3x3 conv + single preh write ---
  const int c8 = lane & 3;                     // this lane's 8-channel octet
  const int cb = hh*HD_ + c8*8;
  h16x8 wk[9];
  #pragma unroll
  for (int kk = 0; kk < 9; ++kk) wk[kk] = *(const h16x8*)&w9t[kk*C_ + cb];
  const h16x8 wbias = *(const h16x8*)&w9t[9*C_ + cb];
  const h16* vb = vmat + (size_t)(b*NH_ + hh)*N_*HD_ + c8*8;
  #pragma unroll
  for (int p = 0; p < 4; ++p) {
    const int tl = p*16 + (lane >> 2);
    const int t  = t0 + tl;
    const int y = t / W_, x0 = t - y*W_;
    h16x8 acc = *(const h16x8*)&Av[tl*40 + c8*8];
    acc += wbias;
    #pragma unroll
    for (int ky = 0; ky < 3; ++ky) {
      #pragma unroll
      for (int kx = 0; kx < 3; ++kx) {
        const int yy = y + ky - 1, xx = x0 + kx - 1;
        const bool ok = ((unsigned)yy < (unsigned)H_) && ((unsigned)xx < (unsigned)W_);
        const int tt = ok ? (yy*W_ + xx) : t;
        const h16x8 vv = *(const h16x8*)&vb[(size_t)tt*HD_];
        const h16x8 w = ok ? wk[ky*3+kx] : (h16x8)(h16)0.f;
        acc += vv * w;
      }
    }
    *(h16x8*)&preh[((size_t)b*N_ + t)*C_ + cb] = acc;
  }
}

// ---------------------------------------------------------------------------
extern "C" void kernel_launch(void* const* d_in, const int* in_sizes, int n_in,
                              void* d_out, int out_size, void* d_ws, size_t ws_size,
                              hipStream_t stream)
{
  (void)in_sizes; (void)n_in; (void)out_size;
  const float* x     = (const float*)d_in[0];
  const float* qkvw  = (const float*)d_in[1];
  const float* qkvb  = (const float*)d_in[2];
  const float* projw = (const float*)d_in[3];
  const float* projb = (const float*)d_in[4];
  const float* dwcw  = (const float*)d_in[5];
  const float* dwcb  = (const float*)d_in[6];
  const float* an    = (const float*)d_in[7];
  const float* na    = (const float*)d_in[8];
  const float* ah    = (const float*)d_in[9];
  const float* aw    = (const float*)d_in[10];
  const float* ha    = (const float*)d_in[11];
  const float* wa    = (const float*)d_in[12];

  const size_t EL = (size_t)B_*N_*C_;
  char* ws = (char*)d_ws;
  h16*   qh    = (h16*)(ws);
  h16*   kh    = (h16*)(ws + EL*2);
  h16*   vh    = (h16*)(ws + EL*4);
  h16*   xh    = (h16*)(ws + EL*6);           // dead after qkv; reused for partials
  h16*   posb  = (h16*)(ws + EL*8);                              // f16, region padded
  h16*   agbt  = (h16*)(ws + EL*8 + (size_t)NH_*A_*N_*4);        // f16, region padded
  float* agent = (float*)(ws + EL*8 + (size_t)NH_*A_*N_*8);
  float* agv   = (float*)(ws + EL*8 + (size_t)NH_*A_*N_*8 + (size_t)B_*NH_*A_*HD_*4);
  h16*   wtq   = (h16*)(ws + EL*8 + (size_t)NH_*A_*N_*8 + (size_t)B_*NH_*A_*HD_*8);
  h16*   wtp   = (h16*)((char*)wtq + (size_t)768*256*2);
  h16*   w9t   = (h16*)((char*)wtp + (size_t)256*256*2);
  const size_t NEED = EL*8 + (size_t)NH_*A_*N_*8 + (size_t)B_*NH_*A_*HD_*8
                    + (size_t)768*256*2 + (size_t)256*256*2 + (size_t)10*256*2;
  if (ws_size < NEED) return;

  float* pm   = (float*)xh;
  float* pl   = pm + (size_t)B_*NH_*NCH_*A_;
  float* pacc = pl + (size_t)B_*NH_*NCH_*A_;
  h16*   preh = kh;

  bias_kernel<<<dim3(NH_*A_), dim3(256), 0, stream>>>(an, na, ah, aw, ha, wa, posb, agbt);
  convx_kernel<<<dim3(4096), dim3(256), 0, stream>>>(x, xh);
  convw_kernel<<<dim3(1034), dim3(256), 0, stream>>>(qkvw, projw, dwcw, dwcb, wtq, wtp, w9t);
  gemm_qkv_mfma<<<dim3(4704), dim3(256), 0, stream>>>(xh, wtq, qkvb, qh, kh, vh);
  pool_kernel<<<dim3(B_*NH_*A_), dim3(64), 0, stream>>>(qh, agent);
  stage1a_mfma<<<dim3(B_*NH_*NCH_), dim3(256), 0, stream>>>(kh, vh, agent, posb, pm, pl, pacc);
  stage1b_kernel<<<dim3(B_*NH_), dim3(256), 0, stream>>>(pm, pl, pacc, agv);
  stage2_mfma<<<dim3(13, B_*NH_), dim3(256), 0, stream>>>(qh, agent, agv, agbt, vh, w9t, preh);
  gemm_proj_mfma<<<dim3(1568), dim3(256), 0, stream>>>(preh, wtp, projb, (float*)d_out);
}

// Round 20
// 278.322 us; speedup vs baseline: 1.1241x; 1.1241x over previous
//
#include <hip/hip_runtime.h>
#include <stdint.h>

#define B_ 32
#define H_ 56
#define W_ 56
#define N_ 3136
#define C_ 256
#define NH_ 8
#define HD_ 32
#define A_ 49
#define NCH_ 7
#define CHK_ 448
#define SCALE_ 0.17677669529663687f

typedef _Float16 h16;
typedef __attribute__((ext_vector_type(4))) _Float16 h16x4;
typedef __attribute__((ext_vector_type(8))) _Float16 h16x8;
typedef __attribute__((ext_vector_type(4))) float f32x4;

// global -> LDS direct DMA, 16B per lane
__device__ __forceinline__ void gload16(const void* g, void* l) {
  __builtin_amdgcn_global_load_lds(
      (const __attribute__((address_space(1))) unsigned int*)(uintptr_t)g,
      (__attribute__((address_space(3))) unsigned int*)(unsigned int)(uintptr_t)l,
      16, 0, 0);
}

// ---------------------------------------------------------------------------
// Bias precompute: position_bias [NH][A][N] f16, agent_bias^T [NH][A][N] f16
// ---------------------------------------------------------------------------
__global__ __launch_bounds__(256)
void bias_kernel(const float* __restrict__ an, const float* __restrict__ na,
                 const float* __restrict__ ah, const float* __restrict__ aw,
                 const float* __restrict__ ha, const float* __restrict__ wa,
                 h16* __restrict__ posb, h16* __restrict__ agbt)
{
  const int hh = blockIdx.x / A_;
  const int ag = blockIdx.x % A_;
  __shared__ float an7[A_], na7[A_], ahv[H_], awv[W_], hav[H_], wav[W_];
  const int tid = threadIdx.x;
  if (tid < A_) {
    an7[tid] = an[(hh*A_ + ag)*A_ + tid];
    na7[tid] = na[(hh*A_ + ag)*A_ + tid];
  }
  if (tid < H_) {
    ahv[tid] = ah[(hh*A_ + ag)*H_ + tid];
    awv[tid] = aw[(hh*A_ + ag)*W_ + tid];
    hav[tid] = ha[(hh*H_ + tid)*A_ + ag];
    wav[tid] = wa[(hh*W_ + tid)*A_ + ag];
  }
  __syncthreads();
  for (int t = tid; t < N_; t += 256) {
    const int ty = t / W_, tx = t % W_;
    const float py = (ty + 0.5f)*0.125f - 0.5f;
    const float px = (tx + 0.5f)*0.125f - 0.5f;
    const int iy = (int)floorf(py), ix = (int)floorf(px);
    const float fy = py - (float)iy, fx = px - (float)ix;
    const int iy0 = min(max(iy, 0), 6), iy1 = min(iy + 1, 6);
    const int ix0 = min(max(ix, 0), 6), ix1 = min(ix + 1, 6);
    const float w00 = (1.f-fy)*(1.f-fx), w01 = (1.f-fy)*fx;
    const float w10 = fy*(1.f-fx),       w11 = fy*fx;
    const float ban = w00*an7[iy0*7+ix0] + w01*an7[iy0*7+ix1]
                    + w10*an7[iy1*7+ix0] + w11*an7[iy1*7+ix1];
    const float bna = w00*na7[iy0*7+ix0] + w01*na7[iy0*7+ix1]
                    + w10*na7[iy1*7+ix0] + w11*na7[iy1*7+ix1];
    posb[((size_t)(hh*A_ + ag))*N_ + t] = (h16)(ban + ahv[ty] + awv[tx]);
    agbt[((size_t)(hh*A_ + ag))*N_ + t] = (h16)(bna + hav[ty] + wav[tx]);
  }
}

// ---------------------------------------------------------------------------
// f32 -> f16 conversion of x
// ---------------------------------------------------------------------------
__global__ __launch_bounds__(256)
void convx_kernel(const float* __restrict__ x, h16* __restrict__ xh)
{
  const size_t nchunk = (size_t)B_*N_*C_/8;
  const size_t stride = (size_t)gridDim.x * 256;
  for (size_t i = blockIdx.x*256 + threadIdx.x; i < nchunk; i += stride) {
    const float4 u = ((const float4*)x)[i*2];
    const float4 v = ((const float4*)x)[i*2+1];
    h16x8 o;
    o[0]=(h16)u.x; o[1]=(h16)u.y; o[2]=(h16)u.z; o[3]=(h16)u.w;
    o[4]=(h16)v.x; o[5]=(h16)v.y; o[6]=(h16)v.z; o[7]=(h16)v.w;
    ((h16x8*)xh)[i] = o;
  }
}

// transpose+convert weights: wtq[768][256], wtp[256][256] f16,
// plus dwc weight table w9t[10][256] f16 (rows 0..8 = taps, row 9 = bias)
__global__ __launch_bounds__(256)
void convw_kernel(const float* __restrict__ qkvw, const float* __restrict__ projw,
                  const float* __restrict__ dwcw, const float* __restrict__ dwcb,
                  h16* __restrict__ wtq, h16* __restrict__ wtp, h16* __restrict__ w9t)
{
  const int bid = blockIdx.x, k = threadIdx.x;
  if (bid < 768) {
    wtq[bid*256 + k] = (h16)qkvw[(size_t)k*768 + bid];
  } else if (bid < 1024) {
    const int n = bid - 768;
    wtp[n*256 + k] = (h16)projw[(size_t)k*256 + n];
  } else {
    const int row = bid - 1024;            // 0..9
    w9t[row*256 + k] = (h16)(row < 9 ? dwcw[k*9 + row] : dwcb[k]);
  }
}

// ---------------------------------------------------------------------------
// f16 MFMA GEMM core: 128x128 tile, BK=32, 4 waves, double-buffered with
// COUNTED vmcnt (T4): stage(next) -> vmcnt(4) -> barrier -> MFMA -> barrier.
// ---------------------------------------------------------------------------
__device__ __forceinline__ void gemm_tile_128(
    const h16* __restrict__ Ag, const h16* __restrict__ Bg,
    int m0, int n0, char* lds, f32x4 acc[4][4], int lane, int wr, int wc, int tid)
{
  int aoff[4], boff[4];
  #pragma unroll
  for (int r = 0; r < 4; ++r) {
    const int row = wr*64 + r*16 + (lane & 15);
    const int ps  = (lane >> 4) ^ ((row >> 1) & 3);
    aoff[r] = row*64 + ps*16;
  }
  #pragma unroll
  for (int c = 0; c < 4; ++c) {
    const int nrow = wc*64 + c*16 + (lane & 15);
    const int ps   = (lane >> 4) ^ ((nrow >> 1) & 3);
    boff[c] = 8192 + nrow*64 + ps*16;
  }
  const int i0 = tid, i1 = tid + 256;
  const int r0 = i0 >> 2, s0 = (i0 & 3) ^ ((r0 >> 1) & 3);
  const int r1 = i1 >> 2, s1 = (i1 & 3) ^ ((r1 >> 1) & 3);

  auto stage = [&](int buf, int k0) {
    char* l = lds + buf*16384;
    gload16(Ag + (size_t)(m0 + r0)*256 + k0 + s0*8, l + i0*16);
    gload16(Ag + (size_t)(m0 + r1)*256 + k0 + s1*8, l + i1*16);
    gload16(Bg + (size_t)(n0 + r0)*256 + k0 + s0*8, l + 8192 + i0*16);
    gload16(Bg + (size_t)(n0 + r1)*256 + k0 + s1*8, l + 8192 + i1*16);
  };

  stage(0, 0);                     // 4 DMAs in flight
  int cur = 0;
  #pragma unroll
  for (int k0 = 0; k0 < 256; k0 += 32) {
    if (k0 + 32 < 256) {
      stage(cur ^ 1, k0 + 32);     // +4 DMAs (next tile)
      asm volatile("s_waitcnt vmcnt(4)" ::: "memory");   // own cur-tile DMAs done
    } else {
      asm volatile("s_waitcnt vmcnt(0)" ::: "memory");
    }
    __builtin_amdgcn_s_barrier();            // all waves' cur-tile writes done
    __builtin_amdgcn_sched_barrier(0);       // fence: no ds_read hoisting
    char* l = lds + cur*16384;
    h16x8 af[4], bf[4];
    #pragma unroll
    for (int r = 0; r < 4; ++r) af[r] = *(const h16x8*)(l + aoff[r]);
    #pragma unroll
    for (int c = 0; c < 4; ++c) bf[c] = *(const h16x8*)(l + boff[c]);
    #pragma unroll
    for (int r = 0; r < 4; ++r)
      #pragma unroll
      for (int c = 0; c < 4; ++c)
        acc[r][c] = __builtin_amdgcn_mfma_f32_16x16x32_f16(af[r], bf[c], acc[r][c], 0, 0, 0);
    __builtin_amdgcn_s_barrier();            // read-release: cur may be overwritten
    cur ^= 1;
  }
}

// QKV: grid 4704 = 784 m-tiles x 6 n-tiles; XCD-bijective swizzle (scalar epilogue)
__global__ __launch_bounds__(256)
void gemm_qkv_mfma(const h16* __restrict__ xh, const h16* __restrict__ wtq,
                   const float* __restrict__ qkvb,
                   h16* __restrict__ q, h16* __restrict__ k, h16* __restrict__ v)
{
  __shared__ __align__(16) char lds[32768];
  const int tid = threadIdx.x, lane = tid & 63, wid = tid >> 6;
  const int wr = wid & 1, wc = wid >> 1;
  const int bid = blockIdx.x;
  const int xcd = bid & 7, j = bid >> 3;           // j in [0,588)
  const int mt = xcd + 8*(j/6), nt = j - 6*(j/6);  // 784 = 98*8 exact
  const int m0 = mt*128, n0 = nt*128;
  f32x4 acc[4][4] = {};
  gemm_tile_128(xh, wtq, m0, n0, lds, acc, lane, wr, wc, tid);
  #pragma unroll
  for (int r = 0; r < 4; ++r) {
    #pragma unroll
    for (int reg = 0; reg < 4; ++reg) {
      const int m = m0 + wr*64 + r*16 + (lane >> 4)*4 + reg;
      const int bb = m / N_, t = m % N_;
      #pragma unroll
      for (int c = 0; c < 4; ++c) {
        const int n = n0 + wc*64 + c*16 + (lane & 15);
        const float val = acc[r][c][reg] + qkvb[n];
        const int part = n >> 8, cc = n & 255, hh = cc >> 5, d = cc & 31;
        h16* dst = (part == 0) ? q : ((part == 1) ? k : v);
        dst[(((size_t)(bb*NH_ + hh))*N_ + t)*HD_ + d] = (h16)val;
      }
    }
  }
}

// Proj: grid 1568 = 784 m-tiles x 2 n-tiles, same swizzle idea
__global__ __launch_bounds__(256)
void gemm_proj_mfma(const h16* __restrict__ preh, const h16* __restrict__ wtp,
                    const float* __restrict__ projb, float* __restrict__ out)
{
  __shared__ __align__(16) char lds[32768];
  const int tid = threadIdx.x, lane = tid & 63, wid = tid >> 6;
  const int wr = wid & 1, wc = wid >> 1;
  const int bid = blockIdx.x;
  const int xcd = bid & 7, j = bid >> 3;           // j in [0,196)
  const int mt = xcd + 8*(j >> 1), nt = j & 1;     // 784 = 98*8 exact
  const int m0 = mt*128, n0 = nt*128;
  f32x4 acc[4][4] = {};
  gemm_tile_128(preh, wtp, m0, n0, lds, acc, lane, wr, wc, tid);
  #pragma unroll
  for (int r = 0; r < 4; ++r) {
    #pragma unroll
    for (int reg = 0; reg < 4; ++reg) {
      const int m = m0 + wr*64 + r*16 + (lane >> 4)*4 + reg;
      #pragma unroll
      for (int c = 0; c < 4; ++c) {
        const int n = n0 + wc*64 + c*16 + (lane & 15);
        out[(size_t)m*256 + n] = acc[r][c][reg] + projb[n];
      }
    }
  }
}

// ---------------------------------------------------------------------------
// Agent pooling: 8x8 mean of q image -> agent [b][nh][49][32] (f32)
// ---------------------------------------------------------------------------
__global__ __launch_bounds__(64)
void pool_kernel(const h16* __restrict__ q, float* __restrict__ agent)
{
  const int blk = blockIdx.x;
  const int ag = blk % A_;
  const int rem = blk / A_;
  const int tid = threadIdx.x;
  const int d = tid & 31, half = tid >> 5;
  const int ay = ag / 7, ax = ag % 7;
  const size_t base = (size_t)rem * N_ * HD_;
  float s = 0.f;
  #pragma unroll
  for (int it = 0; it < 32; ++it) {
    const int yy = half*4 + (it >> 3), xx = it & 7;
    const int t = (ay*8 + yy)*W_ + ax*8 + xx;
    s += (float)q[base + (size_t)t*HD_ + d];
  }
  s += __shfl_down(s, 32, 64);
  if (tid < 32) agent[(size_t)rem*A_*HD_ + ag*HD_ + d] = s * (1.f/64.f);
}

// ---------------------------------------------------------------------------
// Stage 1a (MFMA): flash over 7 key-tiles of 64; M=64 (49 agents + pad)
// ---------------------------------------------------------------------------
__global__ __launch_bounds__(256)
void stage1a_mfma(const h16* __restrict__ kmat, const h16* __restrict__ vmat,
                  const float* __restrict__ agent, const h16* __restrict__ posb,
                  float* __restrict__ pm, float* __restrict__ pl, float* __restrict__ pacc)
{
  __shared__ __align__(16) h16 Kl[64*32];
  __shared__ __align__(16) h16 Vt[32*72];
  __shared__ __align__(16) h16 Sl[64*72];
  const int tid = threadIdx.x, lane = tid & 63, wid = tid >> 6;
  const int bx = blockIdx.x;
  const int ch = bx % NCH_;
  const int rem = bx / NCH_;
  const int hh = rem & 7;
  const size_t kvbase = (size_t)rem * N_ * HD_;
  const size_t agbase = (size_t)rem * A_ * HD_;
  const h16* pb = posb + (size_t)hh*A_*N_;

  const int arow = wid*16 + (lane & 15);
  const int kc = (lane >> 4) * 8;
  h16x8 a_ag = {};
  if (arow < A_) {
    #pragma unroll
    for (int j = 0; j < 8; ++j)
      a_ag[j] = (h16)(agent[agbase + (size_t)arow*HD_ + kc + j] * SCALE_);
  }

  const int r_k = tid >> 2;
  const int s_k = (tid & 3) ^ ((r_k >> 1) & 3);
  const int rowm = (lane >> 4) * 4;
  const int agrow0 = wid*16 + rowm;

  float m_r[4], l_r[4];
  #pragma unroll
  for (int r = 0; r < 4; ++r) { m_r[r] = -1e30f; l_r[r] = 0.f; }
  f32x4 accv[2] = {};

  for (int it = 0; it < 7; ++it) {
    const int t0 = ch*CHK_ + it*64;
    __syncthreads();
    gload16(kmat + kvbase + (size_t)(t0 + r_k)*HD_ + s_k*8, ((char*)Kl) + tid*16);
    const h16x8 vv = *(const h16x8*)&vmat[kvbase + (size_t)(t0 + lane)*HD_ + wid*8];
    #pragma unroll
    for (int j = 0; j < 8; ++j) Vt[(wid*8 + j)*72 + lane] = vv[j];
    __syncthreads();

    float sv[4][4];
    #pragma unroll
    for (int c = 0; c < 4; ++c) {
      const int kr = c*16 + (lane & 15);
      const int ph = (lane >> 4) ^ ((kr >> 1) & 3);
      const h16x8 bf = *(const h16x8*)&Kl[kr*32 + ph*8];
      const f32x4 sc = __builtin_amdgcn_mfma_f32_16x16x32_f16(a_ag, bf, (f32x4){0.f,0.f,0.f,0.f}, 0, 0, 0);
      #pragma unroll
      for (int reg = 0; reg < 4; ++reg) sv[reg][c] = sc[reg];
    }
    #pragma unroll
    for (int reg = 0; reg < 4; ++reg) {
      const int ag = agrow0 + reg;
      if (ag < A_) {
        #pragma unroll
        for (int c = 0; c < 4; ++c)
          sv[reg][c] += (float)pb[(size_t)ag*N_ + t0 + c*16 + (lane & 15)];
      } else {
        #pragma unroll
        for (int c = 0; c < 4; ++c) sv[reg][c] = -1e30f;
      }
      float rm = fmaxf(fmaxf(sv[reg][0], sv[reg][1]), fmaxf(sv[reg][2], sv[reg][3]));
      rm = fmaxf(rm, __shfl_xor(rm, 1));
      rm = fmaxf(rm, __shfl_xor(rm, 2));
      rm = fmaxf(rm, __shfl_xor(rm, 4));
      rm = fmaxf(rm, __shfl_xor(rm, 8));
      const float mn = fmaxf(m_r[reg], rm);
      const float f = __expf(m_r[reg] - mn);
      m_r[reg] = mn;
      float rs = 0.f;
      #pragma unroll
      for (int c = 0; c < 4; ++c) {
        const float p = __expf(sv[reg][c] - mn);
        sv[reg][c] = p;
        rs += p;
      }
      rs += __shfl_xor(rs, 1); rs += __shfl_xor(rs, 2);
      rs += __shfl_xor(rs, 4); rs += __shfl_xor(rs, 8);
      l_r[reg] = l_r[reg]*f + rs;
      accv[0][reg] *= f;
      accv[1][reg] *= f;
      const int row = agrow0 + reg;
      #pragma unroll
      for (int c = 0; c < 4; ++c)
        Sl[row*72 + c*16 + (lane & 15)] = (h16)sv[reg][c];
    }
    __syncthreads();
    const int srow = wid*16 + (lane & 15);
    #pragma unroll
    for (int ks = 0; ks < 2; ++ks) {
      const h16x8 pf = *(const h16x8*)&Sl[srow*72 + ks*32 + (lane >> 4)*8];
      #pragma unroll
      for (int c2 = 0; c2 < 2; ++c2) {
        const int d = c2*16 + (lane & 15);
        const h16x8 vf = *(const h16x8*)&Vt[d*72 + ks*32 + (lane >> 4)*8];
        accv[c2] = __builtin_amdgcn_mfma_f32_16x16x32_f16(pf, vf, accv[c2], 0, 0, 0);
      }
    }
  }

  #pragma unroll
  for (int reg = 0; reg < 4; ++reg) {
    const int ag = agrow0 + reg;
    if (ag < A_) {
      if ((lane & 15) == 0) {
        pm[bx*A_ + ag] = m_r[reg];
        pl[bx*A_ + ag] = l_r[reg];
      }
      #pragma unroll
      for (int c2 = 0; c2 < 2; ++c2)
        pacc[(size_t)bx*(A_*HD_) + (size_t)ag*HD_ + c2*16 + (lane & 15)] = accv[c2][reg];
    }
  }
}

// Stage 1b: combine 7 chunk-partials -> agent_v
__global__ __launch_bounds__(256)
void stage1b_kernel(const float* __restrict__ pm, const float* __restrict__ pl,
                    const float* __restrict__ pacc, float* __restrict__ agv)
{
  const int rem = blockIdx.x;
  __shared__ float fs[NCH_*A_];
  const int tid = threadIdx.x;
  if (tid < A_) {
    float m = -1e30f;
    #pragma unroll
    for (int ch = 0; ch < NCH_; ++ch) m = fmaxf(m, pm[(rem*NCH_+ch)*A_ + tid]);
    float e[NCH_], l = 0.f;
    #pragma unroll
    for (int ch = 0; ch < NCH_; ++ch) {
      e[ch] = __expf(pm[(rem*NCH_+ch)*A_ + tid] - m);
      l += e[ch] * pl[(rem*NCH_+ch)*A_ + tid];
    }
    const float inv = 1.f / l;
    #pragma unroll
    for (int ch = 0; ch < NCH_; ++ch) fs[ch*A_ + tid] = e[ch] * inv;
  }
  __syncthreads();
  for (int idx = tid; idx < A_*HD_; idx += 256) {
    const int ag = idx >> 5;
    float s = 0.f;
    #pragma unroll
    for (int ch = 0; ch < NCH_; ++ch)
      s += fs[ch*A_ + ag] * pacc[((size_t)(rem*NCH_+ch))*(A_*HD_) + idx];
    agv[(size_t)rem*(A_*HD_) + idx] = s;
  }
}

// ---------------------------------------------------------------------------
// Stage 2 (MFMA) + FUSED depthwise conv. Av stride 40 (16B-aligned rows).
// ---------------------------------------------------------------------------
__global__ __launch_bounds__(256)
void stage2_mfma(const h16* __restrict__ qmat, const float* __restrict__ agent,
                 const float* __restrict__ agv, const h16* __restrict__ agbt,
                 const h16* __restrict__ vmat, const h16* __restrict__ w9t,
                 h16* __restrict__ preh)
{
  __shared__ __align__(16) char lds2[45568];
  h16* Asw = (h16*)lds2;                       // [64][32] agent, swizzled, padded
  h16* AVt = (h16*)(lds2 + 4096);              // [32][72] agent_v transposed, padded
  const int tid = threadIdx.x, lane = tid & 63, wid = tid >> 6;
  const int b = blockIdx.y >> 3, hh = blockIdx.y & 7;
  const size_t agbase = (size_t)(b*NH_ + hh)*A_*HD_;

  for (int i = tid; i < 64*32; i += 256) Asw[i] = (h16)0.f;
  for (int i = tid; i < 32*72; i += 256) AVt[i] = (h16)0.f;
  __syncthreads();
  for (int i = tid; i < A_*HD_; i += 256) {
    const int a = i >> 5, d = i & 31;
    Asw[a*32 + (((d >> 3) ^ ((a >> 1) & 3)))*8 + (d & 7)] = (h16)(agent[agbase + i] * SCALE_);
    AVt[d*72 + a] = (h16)agv[agbase + i];
  }
  __syncthreads();

  const int t0 = blockIdx.x*256 + wid*64;
  if (t0 >= N_) return;

  h16* Pl = (h16*)(lds2 + 8704 + wid*9216);    // per-wave [64][72]
  const h16* qbase = qmat + (size_t)(b*NH_ + hh)*N_*HD_;
  const h16* agbt_h = agbt + (size_t)hh*A_*N_;
  const int l15 = lane & 15, g = lane >> 4;

  h16x8 bq[4];
  #pragma unroll
  for (int c = 0; c < 4; ++c) {
    const int a = c*16 + l15;
    const int ph = g ^ ((a >> 1) & 3);
    bq[c] = *(const h16x8*)&Asw[a*32 + ph*8];
  }
  h16x8 aq[4];
  #pragma unroll
  for (int rt = 0; rt < 4; ++rt)
    aq[rt] = *(const h16x8*)&qbase[(size_t)(t0 + rt*16 + l15)*HD_ + g*8];

  f32x4 sc[4][4];
  #pragma unroll
  for (int rt = 0; rt < 4; ++rt)
    #pragma unroll
    for (int c = 0; c < 4; ++c)
      sc[rt][c] = __builtin_amdgcn_mfma_f32_16x16x32_f16(aq[rt], bq[c], (f32x4){0.f,0.f,0.f,0.f}, 0, 0, 0);

  #pragma unroll
  for (int rt = 0; rt < 4; ++rt) {
    float sv[4][4];
    #pragma unroll
    for (int c = 0; c < 4; ++c) {
      const int a = c*16 + l15;
      if (a < A_) {
        const h16x4 bias = *(const h16x4*)&agbt_h[(size_t)a*N_ + t0 + rt*16 + g*4];
        sv[0][c] = sc[rt][c][0] + (float)bias[0];
        sv[1][c] = sc[rt][c][1] + (float)bias[1];
        sv[2][c] = sc[rt][c][2] + (float)bias[2];
        sv[3][c] = sc[rt][c][3] + (float)bias[3];
      } else {
        sv[0][c] = sv[1][c] = sv[2][c] = sv[3][c] = -1e30f;
      }
    }
    #pragma unroll
    for (int reg = 0; reg < 4; ++reg) {
      float rm = fmaxf(fmaxf(sv[reg][0], sv[reg][1]), fmaxf(sv[reg][2], sv[reg][3]));
      rm = fmaxf(rm, __shfl_xor(rm, 1));
      rm = fmaxf(rm, __shfl_xor(rm, 2));
      rm = fmaxf(rm, __shfl_xor(rm, 4));
      rm = fmaxf(rm, __shfl_xor(rm, 8));
      float rs = 0.f;
      #pragma unroll
      for (int c = 0; c < 4; ++c) {
        const float p = __expf(sv[reg][c] - rm);
        sv[reg][c] = p;
        rs += p;
      }
      rs += __shfl_xor(rs, 1); rs += __shfl_xor(rs, 2);
      rs += __shfl_xor(rs, 4); rs += __shfl_xor(rs, 8);
      const float inv = 1.f / rs;
      const int row = rt*16 + g*4 + reg;
      #pragma unroll
      for (int c = 0; c < 4; ++c)
        Pl[row*72 + c*16 + l15] = (h16)(sv[reg][c] * inv);
    }
  }

  h16x8 vf[2][2];
  #pragma unroll
  for (int ks = 0; ks < 2; ++ks)
    #pragma unroll
    for (int c2 = 0; c2 < 2; ++c2)
      vf[ks][c2] = *(const h16x8*)&AVt[(c2*16 + l15)*72 + ks*32 + g*8];

  f32x4 av[4][2] = {};
  #pragma unroll
  for (int rt = 0; rt < 4; ++rt) {
    #pragma unroll
    for (int ks = 0; ks < 2; ++ks) {
      const h16x8 pf = *(const h16x8*)&Pl[(rt*16 + l15)*72 + ks*32 + g*8];
      #pragma unroll
      for (int c2 = 0; c2 < 2; ++c2)
        av[rt][c2] = __builtin_amdgcn_mfma_f32_16x16x32_f16(pf, vf[ks][c2], av[rt][c2], 0, 0, 0);
    }
  }

  // --- transpose av through per-wave LDS (reuse Pl; stride 40 = 80B rows, 16B-aligned) ---
  h16* Av = Pl;                                // [64 tokens][40 h16]
  #pragma unroll
  for (int rt = 0; rt < 4; ++rt)
    #pragma unroll
    for (int c2 = 0; c2 < 2; ++c2)
      #pragma unroll
      for (int reg = 0; reg < 4; ++reg)
        Av[(rt*16 + g*4 + reg)*40 + c2*16 + l15] = (h16)av[rt][c2][reg];

  // --- fused depthwise 3x3 conv + single preh write ---
  const int c8 = lane & 3;                     // this lane's 8-channel octet
  const int cb = hh*HD_ + c8*8;
  h16x8 wk[9];
  #pragma unroll
  for (int kk = 0; kk < 9; ++kk) wk[kk] = *(const h16x8*)&w9t[kk*C_ + cb];
  const h16x8 wbias = *(const h16x8*)&w9t[9*C_ + cb];
  const h16* vb = vmat + (size_t)(b*NH_ + hh)*N_*HD_ + c8*8;
  #pragma unroll
  for (int p = 0; p < 4; ++p) {
    const int tl = p*16 + (lane >> 2);
    const int t  = t0 + tl;
    const int y = t / W_, x0 = t - y*W_;
    h16x8 acc = *(const h16x8*)&Av[tl*40 + c8*8];
    acc += wbias;
    #pragma unroll
    for (int ky = 0; ky < 3; ++ky) {
      #pragma unroll
      for (int kx = 0; kx < 3; ++kx) {
        const int yy = y + ky - 1, xx = x0 + kx - 1;
        const bool ok = ((unsigned)yy < (unsigned)H_) && ((unsigned)xx < (unsigned)W_);
        const int tt = ok ? (yy*W_ + xx) : t;
        const h16x8 vv = *(const h16x8*)&vb[(size_t)tt*HD_];
        const h16x8 w = ok ? wk[ky*3+kx] : (h16x8)(h16)0.f;
        acc += vv * w;
      }
    }
    *(h16x8*)&preh[((size_t)b*N_ + t)*C_ + cb] = acc;
  }
}

// ---------------------------------------------------------------------------
extern "C" void kernel_launch(void* const* d_in, const int* in_sizes, int n_in,
                              void* d_out, int out_size, void* d_ws, size_t ws_size,
                              hipStream_t stream)
{
  (void)in_sizes; (void)n_in; (void)out_size;
  const float* x     = (const float*)d_in[0];
  const float* qkvw  = (const float*)d_in[1];
  const float* qkvb  = (const float*)d_in[2];
  const float* projw = (const float*)d_in[3];
  const float* projb = (const float*)d_in[4];
  const float* dwcw  = (const float*)d_in[5];
  const float* dwcb  = (const float*)d_in[6];
  const float* an    = (const float*)d_in[7];
  const float* na    = (const float*)d_in[8];
  const float* ah    = (const float*)d_in[9];
  const float* aw    = (const float*)d_in[10];
  const float* ha    = (const float*)d_in[11];
  const float* wa    = (const float*)d_in[12];

  const size_t EL = (size_t)B_*N_*C_;
  char* ws = (char*)d_ws;
  h16*   qh    = (h16*)(ws);
  h16*   kh    = (h16*)(ws + EL*2);
  h16*   vh    = (h16*)(ws + EL*4);
  h16*   xh    = (h16*)(ws + EL*6);           // dead after qkv; reused for partials
  h16*   posb  = (h16*)(ws + EL*8);                              // f16, region padded
  h16*   agbt  = (h16*)(ws + EL*8 + (size_t)NH_*A_*N_*4);        // f16, region padded
  float* agent = (float*)(ws + EL*8 + (size_t)NH_*A_*N_*8);
  float* agv   = (float*)(ws + EL*8 + (size_t)NH_*A_*N_*8 + (size_t)B_*NH_*A_*HD_*4);
  h16*   wtq   = (h16*)(ws + EL*8 + (size_t)NH_*A_*N_*8 + (size_t)B_*NH_*A_*HD_*8);
  h16*   wtp   = (h16*)((char*)wtq + (size_t)768*256*2);
  h16*   w9t   = (h16*)((char*)wtp + (size_t)256*256*2);
  const size_t NEED = EL*8 + (size_t)NH_*A_*N_*8 + (size_t)B_*NH_*A_*HD_*8
                    + (size_t)768*256*2 + (size_t)256*256*2 + (size_t)10*256*2;
  if (ws_size < NEED) return;

  float* pm   = (float*)xh;
  float* pl   = pm + (size_t)B_*NH_*NCH_*A_;
  float* pacc = pl + (size_t)B_*NH_*NCH_*A_;
  h16*   preh = kh;

  bias_kernel<<<dim3(NH_*A_), dim3(256), 0, stream>>>(an, na, ah, aw, ha, wa, posb, agbt);
  convx_kernel<<<dim3(4096), dim3(256), 0, stream>>>(x, xh);
  convw_kernel<<<dim3(1034), dim3(256), 0, stream>>>(qkvw, projw, dwcw, dwcb, wtq, wtp, w9t);
  gemm_qkv_mfma<<<dim3(4704), dim3(256), 0, stream>>>(xh, wtq, qkvb, qh, kh, vh);
  pool_kernel<<<dim3(B_*NH_*A_), dim3(64), 0, stream>>>(qh, agent);
  stage1a_mfma<<<dim3(B_*NH_*NCH_), dim3(256), 0, stream>>>(kh, vh, agent, posb, pm, pl, pacc);
  stage1b_kernel<<<dim3(B_*NH_), dim3(256), 0, stream>>>(pm, pl, pacc, agv);
  stage2_mfma<<<dim3(13, B_*NH_), dim3(256), 0, stream>>>(qh, agent, agv, agbt, vh, w9t, preh);
  gemm_proj_mfma<<<dim3(1568), dim3(256), 0, stream>>>(preh, wtp, projb, (float*)d_out);
}